// Round 1
// 262.143 us; speedup vs baseline: 1.0002x; 1.0002x over previous
//
#include <hip/hip_runtime.h>
#include <cstdint>
#include <math.h>

#define N 6144
#define FIN 128
#define FH 64
#define NHEADS 4
#define NC 16
#define CAP 512
#define ALPHA 0.2f
#define NT 16

__device__ __forceinline__ float wave_sum(float v) {
    #pragma unroll
    for (int off = 32; off >= 1; off >>= 1) v += __shfl_xor(v, off);
    return v;
}
__device__ __forceinline__ float wave_max(float v) {
    #pragma unroll
    for (int off = 32; off >= 1; off >>= 1) v = fmaxf(v, __shfl_xor(v, off));
    return v;
}

// Weff[h][k][f] = sum_r W0[h][r*128+k][f]   (x = tile(feature,(1,4)))
__global__ void k_reduce_w(const float* __restrict__ W0, float* __restrict__ weff) {
    int idx = blockIdx.x * 256 + threadIdx.x;           // h*8192 + k*64 + f
    if (idx >= NHEADS * FIN * FH) return;
    int f = idx & 63, k = (idx >> 6) & 127, h = idx >> 13;
    const float* base = W0 + (size_t)h * 512 * 64;
    float s = 0.f;
    #pragma unroll
    for (int r = 0; r < 4; r++) s += base[(size_t)(r * 128 + k) * 64 + f];
    weff[idx] = s;
}

// h_feat[h][n][f] = feature[n] . Weff[h][:,f]; fused s/t = h.a1, h.a2
// One (row-tile, head) per block: 1536 blocks, Weff head staged in LDS,
// k-loop is pure-LDS (no dependent global loads), unrolled x4.
__global__ void k_hgemm(const float* __restrict__ feat, const float* __restrict__ weff,
                        const float* __restrict__ a1, const float* __restrict__ a2,
                        float* __restrict__ hfeat, float* __restrict__ sb,
                        float* __restrict__ tb) {
    __shared__ float fl[NT * FIN];      // 8 KB feature tile
    __shared__ float wl[FIN * FH];      // 32 KB Weff for this head
    int tid = threadIdx.x;
    int h = blockIdx.x & 3;
    int n0 = (blockIdx.x >> 2) * NT;
    for (int idx = tid; idx < NT * FIN; idx += 256) fl[idx] = feat[(size_t)n0 * FIN + idx];
    {
        const float4* wsrc = (const float4*)(weff + (size_t)h * FIN * FH);
        float4* wdst = (float4*)wl;
        for (int idx = tid; idx < FIN * FH / 4; idx += 256) wdst[idx] = wsrc[idx];
    }
    __syncthreads();
    int lane = tid & 63, w = tid >> 6;
    int r0 = w * 4;                      // each wave owns 4 rows x 64 cols
    float acc[4] = {0.f, 0.f, 0.f, 0.f};
    #pragma unroll 2
    for (int k = 0; k < FIN; k += 4) {
        float w0 = wl[(k + 0) * FH + lane];   // coalesced, conflict-free (2-way)
        float w1 = wl[(k + 1) * FH + lane];
        float w2 = wl[(k + 2) * FH + lane];
        float w3 = wl[(k + 3) * FH + lane];
        #pragma unroll
        for (int r = 0; r < 4; r++) {
            float4 fv = *(const float4*)(&fl[(r0 + r) * FIN + k]);  // broadcast
            acc[r] = fmaf(fv.x, w0, acc[r]);
            acc[r] = fmaf(fv.y, w1, acc[r]);
            acc[r] = fmaf(fv.z, w2, acc[r]);
            acc[r] = fmaf(fv.w, w3, acc[r]);
        }
    }
    float a1v = a1[h * FH + lane], a2v = a2[h * FH + lane];
    #pragma unroll
    for (int r = 0; r < 4; r++) {
        int n = n0 + r0 + r;
        hfeat[((size_t)h * N + n) * FH + lane] = acc[r];
        float s = wave_sum(acc[r] * a1v);
        float t = wave_sum(acc[r] * a2v);
        if (lane == 0) {
            sb[h * N + n] = s;
            tb[h * N + n] = t;
        }
    }
}

// Fused per-row megakernel: adj scan (hoisted loads, wave-scan compaction into LDS)
// + hidden-layer online-softmax aggregation (wave = head) + elu
// + output-layer GEMM (x1_row @ Wout) + s2/t2.  Writes cols/deg for k_attn_out.
__global__ void k_row(const float* __restrict__ adj, const float* __restrict__ hfeat,
                      const float* __restrict__ sb, const float* __restrict__ tb,
                      const float* __restrict__ wout, const float* __restrict__ a1o,
                      const float* __restrict__ a2o,
                      int* __restrict__ cols, int* __restrict__ deg,
                      float* __restrict__ h2, float* __restrict__ s2,
                      float* __restrict__ t2) {
    int i = blockIdx.x;
    int tid = threadIdx.x;
    int lane = tid & 63, h = tid >> 6;
    __shared__ int lidx[CAP];
    __shared__ float xrow[NHEADS * FH];
    __shared__ int wtot[4];

    // ---- scan: ALL 6 float4 loads hoisted (independent, in flight together) ----
    const float4* rowv = (const float4*)(adj + (size_t)i * N);
    float4 rv[6];
    #pragma unroll
    for (int it = 0; it < 6; it++) rv[it] = rowv[it * 256 + tid];

    // 24-bit predicate mask per thread, then one scan instead of 24 ballot rounds
    unsigned bm = 0;
    #pragma unroll
    for (int it = 0; it < 6; it++) {
        bm |= (rv[it].x != 0.f ? 1u : 0u) << (it * 4 + 0);
        bm |= (rv[it].y != 0.f ? 1u : 0u) << (it * 4 + 1);
        bm |= (rv[it].z != 0.f ? 1u : 0u) << (it * 4 + 2);
        bm |= (rv[it].w != 0.f ? 1u : 0u) << (it * 4 + 3);
    }
    int cnt_t = __popc(bm);
    int v = cnt_t;                           // inclusive scan over the wave
    #pragma unroll
    for (int s = 1; s < 64; s <<= 1) {
        int u = __shfl_up(v, s);
        if (lane >= s) v += u;
    }
    if (lane == 63) wtot[h] = v;             // wave total
    __syncthreads();
    int base = 0;
    #pragma unroll
    for (int wi = 0; wi < 4; wi++) base += (wi < h) ? wtot[wi] : 0;
    int d = wtot[0] + wtot[1] + wtot[2] + wtot[3];
    int off = base + v - cnt_t;              // exclusive offset for this thread
    unsigned bits = bm;
    while (bits) {
        int b = __ffs(bits) - 1;
        bits &= bits - 1;
        int pos = off++;
        if (pos < CAP) lidx[pos] = (b >> 2) * 1024 + tid * 4 + (b & 3);
    }
    if (tid == 0) deg[i] = d;
    __syncthreads();
    for (int t = tid; t < min(d, CAP); t += 256) cols[(size_t)i * CAP + t] = lidx[t];

    // ---- per-head online-softmax aggregation (quarter-wave: 4 neighbors x float4) ----
    int mode = (d == 0) ? 1 : (d > CAP ? 2 : 0);
    int count = (mode == 0) ? d : N;
    const float* trow = tb + (size_t)h * N;
    const float* hrow = hfeat + (size_t)h * N * FH;
    float si = sb[h * N + i];
    int q = lane >> 4, fo = (lane & 15) * 4;
    float m = -INFINITY, l = 0.f;
    float4 acc = {0.f, 0.f, 0.f, 0.f};
    for (int bb = 0; bb < count; bb += 64) {
        int idx = bb + lane;
        int j = 0; float lr = -INFINITY;
        if (idx < count) {
            j = (mode == 0) ? lidx[idx] : idx;
            bool ok = (mode != 2) || (adj[(size_t)i * N + j] != 0.f);
            if (ok) {
                float z = si + trow[j];
                lr = (z >= 0.f) ? z : ALPHA * z;
            }
        }
        float mc = wave_max(lr);
        float mn = fmaxf(m, mc);
        if (mn == -INFINITY) continue;                   // wave-uniform
        float scale = (m == -INFINITY) ? 0.f : expf(m - mn);
        float w = (lr == -INFINITY) ? 0.f : expf(lr - mn);
        l = l * scale + wave_sum(w);
        acc.x *= scale; acc.y *= scale; acc.z *= scale; acc.w *= scale;
        int cn = min(64, count - bb);
        #pragma unroll 4
        for (int b = 0; b < cn; b += 4) {
            float wb = __shfl(w, b + q);
            int jn = __shfl(j, b + q);
            float4 hv = *(const float4*)(hrow + (size_t)jn * FH + fo);
            acc.x = fmaf(wb, hv.x, acc.x);
            acc.y = fmaf(wb, hv.y, acc.y);
            acc.z = fmaf(wb, hv.z, acc.z);
            acc.w = fmaf(wb, hv.w, acc.w);
        }
        m = mn;
    }
    #pragma unroll
    for (int off2 = 16; off2 <= 32; off2 <<= 1) {
        acc.x += __shfl_xor(acc.x, off2);
        acc.y += __shfl_xor(acc.y, off2);
        acc.z += __shfl_xor(acc.z, off2);
        acc.w += __shfl_xor(acc.w, off2);
    }
    if (lane < 16) {
        float linv = 1.f / l;
        float4 o;
        o.x = acc.x * linv; o.y = acc.y * linv; o.z = acc.z * linv; o.w = acc.w * linv;
        o.x = (o.x > 0.f) ? o.x : expm1f(o.x);
        o.y = (o.y > 0.f) ? o.y : expm1f(o.y);
        o.z = (o.z > 0.f) ? o.z : expm1f(o.z);
        o.w = (o.w > 0.f) ? o.w : expm1f(o.w);
        *(float4*)(xrow + h * FH + fo) = o;              // x1 row stays in LDS
    }
    __syncthreads();

    // ---- fused output GEMM: h2[i] = xrow @ Wout; s2/t2 (wave 0 only) ----
    if (h == 0) {
        int f = lane & 15, part = lane >> 4;
        float dot = 0.f;
        #pragma unroll
        for (int k = 0; k < 64; k++)
            dot = fmaf(xrow[part * 64 + k], wout[(size_t)(part * 64 + k) * NC + f], dot);
        dot += __shfl_xor(dot, 16);
        dot += __shfl_xor(dot, 32);
        if (lane < NC) h2[(size_t)i * NC + lane] = dot;
        float sv = (lane < NC) ? dot * a1o[lane] : 0.f;
        float tv = (lane < NC) ? dot * a2o[lane] : 0.f;
        sv = wave_sum(sv); tv = wave_sum(tv);
        if (lane == 0) { s2[i] = sv; t2[i] = tv; }
    }
}

// Output-layer attention + elu + class softmax. One wave per row, quarter-wave gather.
__global__ void k_attn_out(const float* __restrict__ h2, const float* __restrict__ s2,
                           const float* __restrict__ t2, const int* __restrict__ cols,
                           const int* __restrict__ deg, const float* __restrict__ adj,
                           float* __restrict__ out) {
    int w = threadIdx.x >> 6, lane = threadIdx.x & 63;
    int i = blockIdx.x * 4 + w;
    int d = deg[i];
    int mode = (d == 0) ? 1 : (d > CAP ? 2 : 0);
    int count = (mode == 0) ? d : N;
    const int* crow = cols + (size_t)i * CAP;
    float si = s2[i];
    int f = lane & 15, q = lane >> 4;
    float m = -INFINITY, l = 0.f, acc = 0.f;
    for (int bb = 0; bb < count; bb += 64) {
        int idx = bb + lane;
        int j = 0; float lr = -INFINITY;
        if (idx < count) {
            j = (mode == 0) ? crow[idx] : idx;
            bool ok = (mode != 2) || (adj[(size_t)i * N + j] != 0.f);
            if (ok) {
                float z = si + t2[j];
                lr = (z >= 0.f) ? z : ALPHA * z;
            }
        }
        float mc = wave_max(lr);
        float mn = fmaxf(m, mc);
        if (mn == -INFINITY) continue;
        float scale = (m == -INFINITY) ? 0.f : expf(m - mn);
        float wv = (lr == -INFINITY) ? 0.f : expf(lr - mn);
        l = l * scale + wave_sum(wv);
        acc *= scale;
        int cn = min(64, count - bb);
        #pragma unroll 4
        for (int b = 0; b < cn; b += 4) {
            float wb = __shfl(wv, b + q);
            int jn = __shfl(j, b + q);
            acc = fmaf(wb, h2[(size_t)jn * NC + f], acc);
        }
        m = mn;
    }
    acc += __shfl_xor(acc, 16);
    acc += __shfl_xor(acc, 32);
    float o = acc / l;
    o = (o > 0.f) ? o : expm1f(o);                       // elu
    float mv = (lane < NC) ? o : -INFINITY;
    float mx = wave_max(mv);
    float e = (lane < NC) ? expf(o - mx) : 0.f;
    float se = wave_sum(e);
    if (lane < NC) out[(size_t)i * NC + lane] = e / se;
}

extern "C" void kernel_launch(void* const* d_in, const int* in_sizes, int n_in,
                              void* d_out, int out_size, void* d_ws, size_t ws_size,
                              hipStream_t stream) {
    const float* adj  = (const float*)d_in[0];   // [N,N]
    const float* feat = (const float*)d_in[1];   // [N,128]
    const float* W0   = (const float*)d_in[2];   // [4,512,64]
    const float* a1_0 = (const float*)d_in[3];   // [4,64]
    const float* a2_0 = (const float*)d_in[4];   // [4,64]
    const float* Wout = (const float*)d_in[5];   // [256,16]
    const float* a1o  = (const float*)d_in[6];   // [16]
    const float* a2o  = (const float*)d_in[7];   // [16]
    float* out = (float*)d_out;                  // [N,16]

    float* weff  = (float*)d_ws;                 // 32768
    float* hfeat = weff + 32768;                 // 4*6144*64 = 1572864
    float* sb    = hfeat + 1572864;              // 24576
    float* tb    = sb + 24576;                   // 24576
    float* h2    = tb + 24576;                   // 6144*16 = 98304
    float* s2    = h2 + 98304;                   // 6144
    float* t2    = s2 + 6144;                    // 6144
    int*   cols  = (int*)(t2 + 6144);            // 6144*512
    int*   deg   = cols + (size_t)N * CAP;       // 6144

    k_reduce_w<<<128, 256, 0, stream>>>(W0, weff);
    k_hgemm<<<(N / NT) * NHEADS, 256, 0, stream>>>(feat, weff, a1_0, a2_0, hfeat, sb, tb);
    k_row<<<N, 256, 0, stream>>>(adj, hfeat, sb, tb, Wout, a1o, a2o,
                                 cols, deg, h2, s2, t2);
    k_attn_out<<<N / 4, 256, 0, stream>>>(h2, s2, t2, cols, deg, adj, out);
}